// Round 4
// baseline (216.496 us; speedup 1.0000x reference)
//
#include <hip/hip_runtime.h>
#include <hip/hip_bf16.h>
#include <stdint.h>

#define Bc 4
#define Sc 2048
#define Dc 1024
#define Hc 16
#define HDc 64
#define LOG2E 1.44269504088896f

typedef __attribute__((ext_vector_type(8))) __bf16 bf16x8;
typedef __attribute__((ext_vector_type(4))) __bf16 bf16x4;
typedef __attribute__((ext_vector_type(4))) float f32x4;
typedef __attribute__((ext_vector_type(16))) float f32x16;
typedef __attribute__((ext_vector_type(2))) int i32x2_t;

__device__ __forceinline__ f32x4 mfma16(bf16x8 a, bf16x8 b, f32x4 c) {
  return __builtin_amdgcn_mfma_f32_16x16x32_bf16(a, b, c, 0, 0, 0);
}
__device__ __forceinline__ f32x16 mfma32(bf16x8 a, bf16x8 b, f32x16 c) {
  return __builtin_amdgcn_mfma_f32_32x32x16_bf16(a, b, c, 0, 0, 0);
}
__device__ __forceinline__ uint32_t cvtpk_bf16(float lo, float hi) {
  uint32_t r;
  asm("v_cvt_pk_bf16_f32 %0, %1, %2" : "=v"(r) : "v"(lo), "v"(hi));
  return r;
}
__device__ __forceinline__ void gload_lds16(const void* g, void* l) {
  __builtin_amdgcn_global_load_lds(
      (const __attribute__((address_space(1))) void*)g,
      (__attribute__((address_space(3))) void*)l, 16, 0, 0);
}

// ---------------- Kernel 0: hs (fp32) -> bf16 ----------------
__global__ __launch_bounds__(256) void hs2bf_kernel(const float* __restrict__ hs,
                                                    __bf16* __restrict__ Ah) {
  const size_t i = ((size_t)blockIdx.x * 256 + threadIdx.x) * 8;
  float4 f0 = *(const float4*)(hs + i);
  float4 f1 = *(const float4*)(hs + i + 4);
  bf16x8 o;
  o[0] = (__bf16)f0.x; o[1] = (__bf16)f0.y; o[2] = (__bf16)f0.z; o[3] = (__bf16)f0.w;
  o[4] = (__bf16)f1.x; o[5] = (__bf16)f1.y; o[6] = (__bf16)f1.z; o[7] = (__bf16)f1.w;
  *(bf16x8*)(Ah + i) = o;
}

// ---------------- Kernel 1: Wt[w][n][k] = (bf16) W[w][k][n] ----------------
__global__ __launch_bounds__(256) void wtrans_kernel(
    const float* __restrict__ Wq, const float* __restrict__ Wk,
    const float* __restrict__ Wv, __bf16* __restrict__ Wt) {
  const float* W = (blockIdx.z == 0) ? Wq : (blockIdx.z == 1 ? Wk : Wv);
  __bf16* out = Wt + (size_t)blockIdx.z * Dc * Dc;
  const int n0 = blockIdx.x * 64, k0 = blockIdx.y * 64;
  __shared__ float tile[64][65];
  const int tid = threadIdx.x;
  const int r = tid >> 2, cs = (tid & 3) * 16;
  const float* src = W + (size_t)(k0 + r) * Dc + n0 + cs;
  float4 f0 = *(const float4*)(src + 0);
  float4 f1 = *(const float4*)(src + 4);
  float4 f2 = *(const float4*)(src + 8);
  float4 f3 = *(const float4*)(src + 12);
#pragma unroll
  for (int j = 0; j < 4; ++j) {
    tile[r][cs + j] = ((const float*)&f0)[j];
    tile[r][cs + 4 + j] = ((const float*)&f1)[j];
    tile[r][cs + 8 + j] = ((const float*)&f2)[j];
    tile[r][cs + 12 + j] = ((const float*)&f3)[j];
  }
  __syncthreads();
  bf16x8 o0, o1;
#pragma unroll
  for (int j = 0; j < 8; ++j) {
    o0[j] = (__bf16)tile[cs + j][r];
    o1[j] = (__bf16)tile[cs + 8 + j][r];
  }
  __bf16* dst = out + (size_t)(n0 + r) * Dc + k0 + cs;
  *(bf16x8*)(dst) = o0;
  *(bf16x8*)(dst + 8) = o1;
}

// ---------------- Kernel 2: fused QKV GEMM (bf16 A, global_load_lds, dbuf) --
// Q written PRE-SCALED by (1/8)*log2(e) (softmax scale + exp2 base folded in).
// Q,K: [B,H,S,HD]; V transposed: [B,H,HD,S].
__global__ __launch_bounds__(256) void qkv_gemm_kernel(
    const __bf16* __restrict__ A, const __bf16* __restrict__ Wt,
    const float* __restrict__ bq, const float* __restrict__ bk,
    const float* __restrict__ bv,
    __bf16* __restrict__ Qo, __bf16* __restrict__ Ko, __bf16* __restrict__ Vt) {
  const int orig = blockIdx.x;
  const int nt = orig & 7;
  const int rest = orig >> 3;        // 0..191
  const int w = rest >> 6;           // 0..2
  const int mt = rest & 63;          // 0..63
  const int m0 = mt * 128, n0 = nt * 128;

  const __bf16* Bp = Wt + (size_t)w * Dc * Dc;
  const float* bias = (w == 0) ? bq : (w == 1 ? bk : bv);

  __shared__ __attribute__((aligned(16))) __bf16 Asm[2][128 * 32];
  __shared__ __attribute__((aligned(16))) __bf16 Bsm[2][128 * 32];

  const int tid = threadIdx.x, lane = tid & 63, wid = tid >> 6;
  const int wm = wid >> 1, wn = wid & 1;
  const int lg = lane >> 4, li = lane & 15;

  f32x4 acc[4][4] = {};

  auto stage = [&](int buf, int k0) {
#pragma unroll
    for (int i = 0; i < 2; ++i) {
      const int u = i * 256 + tid;
      const int row = u >> 2, c = u & 3;
      const int gc = c ^ (row & 3);
      gload_lds16(A + (size_t)(m0 + row) * Dc + k0 + gc * 8,
                  &Asm[buf][i * 2048 + wid * 512]);
      gload_lds16(Bp + (size_t)(n0 + row) * Dc + k0 + gc * 8,
                  &Bsm[buf][i * 2048 + wid * 512]);
    }
  };

  int cur = 0;
  stage(0, 0);
  __syncthreads();

  for (int k0 = 0; k0 < Dc; k0 += 32) {
    if (k0 + 32 < Dc) stage(cur ^ 1, k0 + 32);
    bf16x8 af[4], bfr[4];
#pragma unroll
    for (int i = 0; i < 4; ++i) {
      const int rowa = wm * 64 + i * 16 + li;
      af[i] = *(const bf16x8*)&Asm[cur][rowa * 32 + (lg ^ (rowa & 3)) * 8];
      const int rowb = wn * 64 + i * 16 + li;
      bfr[i] = *(const bf16x8*)&Bsm[cur][rowb * 32 + (lg ^ (rowb & 3)) * 8];
    }
#pragma unroll
    for (int i = 0; i < 4; ++i)
#pragma unroll
      for (int j = 0; j < 4; ++j)
        acc[i][j] = mfma16(af[i], bfr[j], acc[i][j]);
    __syncthreads();
    cur ^= 1;
  }

  if (w < 2) {
    __bf16* out = (w == 0) ? Qo : Ko;
    const float scl = (w == 0) ? (0.125f * LOG2E) : 1.0f;
#pragma unroll
    for (int i = 0; i < 4; ++i) {
#pragma unroll
      for (int j = 0; j < 4; ++j) {
        const int n = n0 + wn * 64 + j * 16 + li;
        const float bb = bias[n];
        const int h = n >> 6, hd = n & 63;
#pragma unroll
        for (int r = 0; r < 4; ++r) {
          const int m = m0 + wm * 64 + i * 16 + lg * 4 + r;
          const int b = m >> 11, s = m & 2047;
          out[(((size_t)b * Hc + h) * Sc + s) * HDc + hd] =
              (__bf16)((acc[i][j][r] + bb) * scl);
        }
      }
    }
  } else {
    // V transposed: Vt[b][h][hd][s], 4 consecutive s per lane -> 8B store
#pragma unroll
    for (int i = 0; i < 4; ++i) {
      const int mbase = m0 + wm * 64 + i * 16 + lg * 4;
      const int b = mbase >> 11, s0 = mbase & 2047;
#pragma unroll
      for (int j = 0; j < 4; ++j) {
        const int n = n0 + wn * 64 + j * 16 + li;
        const float bb = bias[n];
        const int h = n >> 6, hd = n & 63;
        bf16x4 o;
#pragma unroll
        for (int r = 0; r < 4; ++r) o[r] = (__bf16)(acc[i][j][r] + bb);
        *(bf16x4*)(Vt + (((size_t)b * Hc + h) * HDc + hd) * Sc + s0) = o;
      }
    }
  }
}

// ---------------- Kernel 3: attention (swapped-QK, in-register softmax) -----
// Block = (qtile of 128 rows) x (b,h). 4 waves x 32 q-rows. KV tile 64.
// LDS holds K/V in MFMA FRAGMENT ORDER (global source pre-permuted so
// global_load_lds's linear base+lane*16 dest lands fragments contiguously):
//   K slot s: kb2=s>>8, c=(s>>6)&3, hi=(s>>5)&1, qr=s&31
//     holds K[kb2*32+qr][c*16+hi*8 ..+7]  -> read base+(kb2*4+c)*1024B+lane*16
//   V slot s: kc=s>>7, nb=(s>>6)&1, hi=(s>>5)&1, qr=s&31
//     holds Vt[nb*32+qr][kv0+kc*16+hi*8 ..+7] -> read base+(kc*2+nb)*1024B+lane*16
// All MFMA-feeding ds_read_b128 are lane-consecutive => zero bank conflicts.
// Softmax in exp2 domain: Q pre-scaled by log2e/8, mask staged *log2e.
__global__ __launch_bounds__(256) void attn_kernel(
    const __bf16* __restrict__ Q, const __bf16* __restrict__ K,
    const __bf16* __restrict__ Vt, const float* __restrict__ mask,
    float* __restrict__ out) {
  const int qt = blockIdx.x;   // 0..15
  const int bh = blockIdx.y;   // 0..63
  const int b = bh >> 4, h = bh & 15;
  const __bf16* qb = Q + (size_t)bh * Sc * HDc;
  const __bf16* kb = K + (size_t)bh * Sc * HDc;
  const __bf16* vtb = Vt + (size_t)bh * HDc * Sc;
  const float* mk = mask + (size_t)b * Sc;

  const int tid = threadIdx.x, lane = tid & 63, wid = tid >> 6;
  const int hi = lane >> 5, qr = lane & 31;

  __shared__ __attribute__((aligned(16))) __bf16 Ksm[2][64 * 64];
  __shared__ __attribute__((aligned(16))) __bf16 Vsm[2][64 * 64];
  __shared__ __attribute__((aligned(16))) float Msm[2][64];

  const int q0 = qt * 128 + wid * 32;

  // Q as B-operand frags (pre-scaled by log2e/8)
  bf16x8 qf[4];
#pragma unroll
  for (int c = 0; c < 4; ++c)
    qf[c] = *(const bf16x8*)(qb + (size_t)(q0 + qr) * HDc + c * 16 + hi * 8);

  bf16x8 onesv;
#pragma unroll
  for (int j = 0; j < 8; ++j) onesv[j] = (__bf16)1.0f;

  f32x16 oacc[2] = {};
  f32x16 lacc = {};

  auto stage = [&](int buf, int kv0) {
#pragma unroll
    for (int i = 0; i < 2; ++i) {
      const int s = i * 256 + tid;
      const int sqr = s & 31, shi = (s >> 5) & 1;
      // K fragment-order source
      gload_lds16(kb + (size_t)(kv0 + (s >> 8) * 32 + sqr) * HDc +
                      ((s >> 6) & 3) * 16 + shi * 8,
                  &Ksm[buf][(i * 256 + wid * 64) * 8]);
      // V fragment-order source
      gload_lds16(vtb + (size_t)(((s >> 6) & 1) * 32 + sqr) * Sc + kv0 +
                      (s >> 7) * 16 + shi * 8,
                  &Vsm[buf][(i * 256 + wid * 64) * 8]);
    }
    if (tid < 16) {
      float4 mv = *(const float4*)(mk + kv0 + tid * 4);
      mv.x *= LOG2E; mv.y *= LOG2E; mv.z *= LOG2E; mv.w *= LOG2E;
      *(float4*)&Msm[buf][tid * 4] = mv;
    }
  };

  auto body = [&](int buf) {
    const __bf16* Kb = &Ksm[buf][lane * 8];
    const __bf16* Vb = &Vsm[buf][lane * 8];
    // C-init = mask*log2e (per-key), then sacc = (QK/8 + mask)*log2e
    f32x16 sacc[2];
#pragma unroll
    for (int kb2 = 0; kb2 < 2; ++kb2) {
#pragma unroll
      for (int g = 0; g < 4; ++g) {
        const float4 m4 = *(const float4*)&Msm[buf][kb2 * 32 + g * 8 + hi * 4];
#pragma unroll
        for (int e = 0; e < 4; ++e) sacc[kb2][g * 4 + e] = ((const float*)&m4)[e];
      }
    }
    __builtin_amdgcn_s_setprio(1);
#pragma unroll
    for (int kb2 = 0; kb2 < 2; ++kb2) {
#pragma unroll
      for (int c = 0; c < 4; ++c) {
        const bf16x8 kf = *(const bf16x8*)(Kb + (kb2 * 4 + c) * 512);
        sacc[kb2] = mfma32(kf, qf[c], sacc[kb2]);
      }
    }
    __builtin_amdgcn_s_setprio(0);

    // P = exp2(sacc); pack to bf16 A-frags via cvt_pk + permlane32_swap
    bf16x8 pa[4];
#pragma unroll
    for (int kb2 = 0; kb2 < 2; ++kb2) {
      uint32_t wv[8];
#pragma unroll
      for (int j = 0; j < 8; ++j)
        wv[j] = cvtpk_bf16(__builtin_amdgcn_exp2f(sacc[kb2][2 * j]),
                           __builtin_amdgcn_exp2f(sacc[kb2][2 * j + 1]));
#pragma unroll
      for (int cc = 0; cc < 2; ++cc) {
        i32x2_t s02 = __builtin_amdgcn_permlane32_swap(
            (int)wv[cc * 4 + 0], (int)wv[cc * 4 + 2], false, false);
        i32x2_t s13 = __builtin_amdgcn_permlane32_swap(
            (int)wv[cc * 4 + 1], (int)wv[cc * 4 + 3], false, false);
        union { uint32_t u[4]; bf16x8 v; } af;
        af.u[0] = (uint32_t)s02[0];
        af.u[1] = (uint32_t)s13[0];
        af.u[2] = (uint32_t)s02[1];
        af.u[3] = (uint32_t)s13[1];
        pa[kb2 * 2 + cc] = af.v;
      }
    }

    // PV + ones-MFMA row-sum
    __builtin_amdgcn_s_setprio(1);
#pragma unroll
    for (int kc = 0; kc < 4; ++kc) {
      lacc = mfma32(pa[kc], onesv, lacc);
#pragma unroll
      for (int nb = 0; nb < 2; ++nb) {
        const bf16x8 vf = *(const bf16x8*)(Vb + (kc * 2 + nb) * 512);
        oacc[nb] = mfma32(pa[kc], vf, oacc[nb]);
      }
    }
    __builtin_amdgcn_s_setprio(0);
    __syncthreads();
  };

  stage(0, 0);
  __syncthreads();

  const int NT = Sc / 64;  // 32, even
  for (int t = 0; t < NT; t += 2) {
    if (t + 1 < NT) stage(1, (t + 1) * 64);
    body(0);
    if (t + 2 < NT) stage(0, (t + 2) * 64);
    body(1);
  }

  // normalize + store
  float inv[16];
#pragma unroll
  for (int r = 0; r < 16; ++r) inv[r] = __builtin_amdgcn_rcpf(lacc[r]);
#pragma unroll
  for (int nb = 0; nb < 2; ++nb) {
#pragma unroll
    for (int r = 0; r < 16; ++r) {
      const int row = (r & 3) + 8 * (r >> 2) + 4 * hi;
      const int qg = q0 + row;
      out[((size_t)b * Sc + qg) * Dc + h * HDc + nb * 32 + qr] =
          oacc[nb][r] * inv[r];
    }
  }
}

// ---------------- launch ----------------
extern "C" void kernel_launch(void* const* d_in, const int* in_sizes, int n_in,
                              void* d_out, int out_size, void* d_ws,
                              size_t ws_size, hipStream_t stream) {
  const float* hs = (const float*)d_in[0];
  const float* mask = (const float*)d_in[1];
  const float* Wq = (const float*)d_in[2];
  const float* bq = (const float*)d_in[3];
  const float* Wk = (const float*)d_in[4];
  const float* bk = (const float*)d_in[5];
  const float* Wv = (const float*)d_in[6];
  const float* bv = (const float*)d_in[7];
  float* out = (float*)d_out;

  char* ws = (char*)d_ws;
  const size_t qkv_bytes = (size_t)Bc * Hc * Sc * HDc * 2;  // 16.78 MB
  __bf16* Wt = (__bf16*)ws;                                 // 6 MB
  __bf16* Ah = (__bf16*)(ws + 6291456);                     // 16.78 MB
  __bf16* Q = (__bf16*)(ws + 6291456 + qkv_bytes);
  __bf16* K = (__bf16*)(ws + 6291456 + 2 * qkv_bytes);
  __bf16* Vt = (__bf16*)(ws + 6291456 + 3 * qkv_bytes);

  hs2bf_kernel<<<4096, 256, 0, stream>>>(hs, Ah);
  wtrans_kernel<<<dim3(16, 16, 3), 256, 0, stream>>>(Wq, Wk, Wv, Wt);
  qkv_gemm_kernel<<<1536, 256, 0, stream>>>(Ah, Wt, bq, bk, bv, Q, K, Vt);
  attn_kernel<<<dim3(16, 64), 256, 0, stream>>>(Q, K, Vt, mask, out);
}

// Round 5
// 211.151 us; speedup vs baseline: 1.0253x; 1.0253x over previous
//
#include <hip/hip_runtime.h>
#include <hip/hip_bf16.h>
#include <stdint.h>

#define Bc 4
#define Sc 2048
#define Dc 1024
#define Hc 16
#define HDc 64
#define LOG2E 1.44269504088896f

typedef __attribute__((ext_vector_type(8))) __bf16 bf16x8;
typedef __attribute__((ext_vector_type(4))) __bf16 bf16x4;
typedef __attribute__((ext_vector_type(4))) float f32x4;
typedef __attribute__((ext_vector_type(16))) float f32x16;
typedef __attribute__((ext_vector_type(2))) int i32x2_t;

__device__ __forceinline__ f32x4 mfma16(bf16x8 a, bf16x8 b, f32x4 c) {
  return __builtin_amdgcn_mfma_f32_16x16x32_bf16(a, b, c, 0, 0, 0);
}
__device__ __forceinline__ f32x16 mfma32(bf16x8 a, bf16x8 b, f32x16 c) {
  return __builtin_amdgcn_mfma_f32_32x32x16_bf16(a, b, c, 0, 0, 0);
}
__device__ __forceinline__ uint32_t cvtpk_bf16(float lo, float hi) {
  uint32_t r;
  asm("v_cvt_pk_bf16_f32 %0, %1, %2" : "=v"(r) : "v"(lo), "v"(hi));
  return r;
}
__device__ __forceinline__ void gload_lds16(const void* g, void* l) {
  __builtin_amdgcn_global_load_lds(
      (const __attribute__((address_space(1))) void*)g,
      (__attribute__((address_space(3))) void*)l, 16, 0, 0);
}
__device__ __forceinline__ void gload_lds4(const void* g, void* l) {
  __builtin_amdgcn_global_load_lds(
      (const __attribute__((address_space(1))) void*)g,
      (__attribute__((address_space(3))) void*)l, 4, 0, 0);
}

// ---------------- Kernel 0a: mask * log2e ----------------
__global__ __launch_bounds__(256) void maskscale_kernel(const float* __restrict__ m,
                                                        float* __restrict__ mkx) {
  const int i = blockIdx.x * 256 + threadIdx.x;  // 8192 total
  mkx[i] = m[i] * LOG2E;
}

// ---------------- Kernel 0b: hs (fp32) -> bf16 ----------------
__global__ __launch_bounds__(256) void hs2bf_kernel(const float* __restrict__ hs,
                                                    __bf16* __restrict__ Ah) {
  const size_t i = ((size_t)blockIdx.x * 256 + threadIdx.x) * 8;
  float4 f0 = *(const float4*)(hs + i);
  float4 f1 = *(const float4*)(hs + i + 4);
  bf16x8 o;
  o[0] = (__bf16)f0.x; o[1] = (__bf16)f0.y; o[2] = (__bf16)f0.z; o[3] = (__bf16)f0.w;
  o[4] = (__bf16)f1.x; o[5] = (__bf16)f1.y; o[6] = (__bf16)f1.z; o[7] = (__bf16)f1.w;
  *(bf16x8*)(Ah + i) = o;
}

// ---------------- Kernel 1: Wt[w][n][k] = (bf16) W[w][k][n] ----------------
__global__ __launch_bounds__(256) void wtrans_kernel(
    const float* __restrict__ Wq, const float* __restrict__ Wk,
    const float* __restrict__ Wv, __bf16* __restrict__ Wt) {
  const float* W = (blockIdx.z == 0) ? Wq : (blockIdx.z == 1 ? Wk : Wv);
  __bf16* out = Wt + (size_t)blockIdx.z * Dc * Dc;
  const int n0 = blockIdx.x * 64, k0 = blockIdx.y * 64;
  __shared__ float tile[64][65];
  const int tid = threadIdx.x;
  const int r = tid >> 2, cs = (tid & 3) * 16;
  const float* src = W + (size_t)(k0 + r) * Dc + n0 + cs;
  float4 f0 = *(const float4*)(src + 0);
  float4 f1 = *(const float4*)(src + 4);
  float4 f2 = *(const float4*)(src + 8);
  float4 f3 = *(const float4*)(src + 12);
#pragma unroll
  for (int j = 0; j < 4; ++j) {
    tile[r][cs + j] = ((const float*)&f0)[j];
    tile[r][cs + 4 + j] = ((const float*)&f1)[j];
    tile[r][cs + 8 + j] = ((const float*)&f2)[j];
    tile[r][cs + 12 + j] = ((const float*)&f3)[j];
  }
  __syncthreads();
  bf16x8 o0, o1;
#pragma unroll
  for (int j = 0; j < 8; ++j) {
    o0[j] = (__bf16)tile[cs + j][r];
    o1[j] = (__bf16)tile[cs + 8 + j][r];
  }
  __bf16* dst = out + (size_t)(n0 + r) * Dc + k0 + cs;
  *(bf16x8*)(dst) = o0;
  *(bf16x8*)(dst + 8) = o1;
}

// ---------------- Kernel 2: fused QKV GEMM ----------------
// Q: [B,H,S,HD] pre-scaled by log2e/8.
// K: fragment-order Kf[bh][t][slot]*8+j8, slot=(kt>>5)*256+c*64+shi*32+(kt&31),
//    element j8 holds K[key=t*64+kb2*32+sqr][hd=c*16+shi*8+j8].
// V: fragment-order Vf[bh][t][slot]*8+j,  slot=kc*128+nb*64+shi*32+sqr,
//    element j holds V[key=t*64+kc*16+shi*8+j][hd=nb*32+sqr].
__global__ __launch_bounds__(256) void qkv_gemm_kernel(
    const __bf16* __restrict__ A, const __bf16* __restrict__ Wt,
    const float* __restrict__ bq, const float* __restrict__ bk,
    const float* __restrict__ bv,
    __bf16* __restrict__ Qo, __bf16* __restrict__ Kf, __bf16* __restrict__ Vf) {
  const int orig = blockIdx.x;
  const int nt = orig & 7;
  const int rest = orig >> 3;        // 0..191
  const int w = rest >> 6;           // 0..2
  const int mt = rest & 63;          // 0..63
  const int m0 = mt * 128, n0 = nt * 128;

  const __bf16* Bp = Wt + (size_t)w * Dc * Dc;
  const float* bias = (w == 0) ? bq : (w == 1 ? bk : bv);

  __shared__ __attribute__((aligned(16))) __bf16 Asm[2][128 * 32];
  __shared__ __attribute__((aligned(16))) __bf16 Bsm[2][128 * 32];

  const int tid = threadIdx.x, lane = tid & 63, wid = tid >> 6;
  const int wm = wid >> 1, wn = wid & 1;
  const int lg = lane >> 4, li = lane & 15;

  f32x4 acc[4][4] = {};

  auto stage = [&](int buf, int k0) {
#pragma unroll
    for (int i = 0; i < 2; ++i) {
      const int u = i * 256 + tid;
      const int row = u >> 2, c = u & 3;
      const int gc = c ^ (row & 3);
      gload_lds16(A + (size_t)(m0 + row) * Dc + k0 + gc * 8,
                  &Asm[buf][i * 2048 + wid * 512]);
      gload_lds16(Bp + (size_t)(n0 + row) * Dc + k0 + gc * 8,
                  &Bsm[buf][i * 2048 + wid * 512]);
    }
  };

  int cur = 0;
  stage(0, 0);
  __syncthreads();

  for (int k0 = 0; k0 < Dc; k0 += 32) {
    if (k0 + 32 < Dc) stage(cur ^ 1, k0 + 32);
    bf16x8 af[4], bfr[4];
#pragma unroll
    for (int i = 0; i < 4; ++i) {
      const int rowa = wm * 64 + i * 16 + li;
      af[i] = *(const bf16x8*)&Asm[cur][rowa * 32 + (lg ^ (rowa & 3)) * 8];
      const int rowb = wn * 64 + i * 16 + li;
      bfr[i] = *(const bf16x8*)&Bsm[cur][rowb * 32 + (lg ^ (rowb & 3)) * 8];
    }
#pragma unroll
    for (int i = 0; i < 4; ++i)
#pragma unroll
      for (int j = 0; j < 4; ++j)
        acc[i][j] = mfma16(af[i], bfr[j], acc[i][j]);
    __syncthreads();
    cur ^= 1;
  }

  if (w == 0) {
    const float scl = 0.125f * LOG2E;
#pragma unroll
    for (int i = 0; i < 4; ++i) {
#pragma unroll
      for (int j = 0; j < 4; ++j) {
        const int n = n0 + wn * 64 + j * 16 + li;
        const float bb = bias[n];
        const int h = n >> 6, hd = n & 63;
#pragma unroll
        for (int r = 0; r < 4; ++r) {
          const int m = m0 + wm * 64 + i * 16 + lg * 4 + r;
          const int b = m >> 11, s = m & 2047;
          Qo[(((size_t)b * Hc + h) * Sc + s) * HDc + hd] =
              (__bf16)((acc[i][j][r] + bb) * scl);
        }
      }
    }
  } else if (w == 1) {
    // K fragment-order scatter (2B stores, same count as plain layout)
#pragma unroll
    for (int j = 0; j < 4; ++j) {
      const int n = n0 + wn * 64 + j * 16 + li;
      const float bb = bias[n];
      const int h = n >> 6, hd = n & 63;
      const int c = hd >> 4, shi = (hd >> 3) & 1, j8 = hd & 7;
#pragma unroll
      for (int i = 0; i < 4; ++i) {
#pragma unroll
        for (int r = 0; r < 4; ++r) {
          const int m = m0 + wm * 64 + i * 16 + lg * 4 + r;
          const int b = m >> 11, s = m & 2047;
          const int bh = b * Hc + h;
          const int t = s >> 6, kt = s & 63;
          const int slot = (kt >> 5) * 256 + c * 64 + shi * 32 + (kt & 31);
          Kf[((size_t)(bh * 32 + t)) * 4096 + slot * 8 + j8] =
              (__bf16)(acc[i][j][r] + bb);
        }
      }
    }
  } else {
    // V fragment-order: 4 consecutive keys per lane -> 8B store
#pragma unroll
    for (int i = 0; i < 4; ++i) {
      const int mbase = m0 + wm * 64 + i * 16 + lg * 4;
      const int b = mbase >> 11, sk = mbase & 2047;
      const int t = sk >> 6, kt = sk & 63;
      const int kc = kt >> 4, shi = (kt >> 3) & 1, j0 = kt & 7;  // j0 in {0,4}
#pragma unroll
      for (int j = 0; j < 4; ++j) {
        const int n = n0 + wn * 64 + j * 16 + li;
        const float bb = bias[n];
        const int h = n >> 6, hd = n & 63;
        const int nb = hd >> 5, sqr = hd & 31;
        const int bh = b * Hc + h;
        const int slot = kc * 128 + nb * 64 + shi * 32 + sqr;
        bf16x4 o;
#pragma unroll
        for (int r = 0; r < 4; ++r) o[r] = (__bf16)(acc[i][j][r] + bb);
        *(bf16x4*)&Vf[((size_t)(bh * 32 + t)) * 4096 + slot * 8 + j0] = o;
      }
    }
  }
}

// ---------------- Kernel 3: attention ----------------
// Swapped-QK in-register softmax; K/V already in fragment order in global
// (linear coalesced gload_lds, zero LDS conflicts, zero addr math).
// 3 LDS buffers, 2-tile-ahead prefetch, counted vmcnt (no drain in loop).
__global__ __launch_bounds__(256) void attn_kernel(
    const __bf16* __restrict__ Q, const __bf16* __restrict__ Kf,
    const __bf16* __restrict__ Vf, const float* __restrict__ mkx,
    float* __restrict__ out) {
  const int qt = blockIdx.x;   // 0..15
  const int bh = blockIdx.y;   // 0..63
  const int b = bh >> 4, h = bh & 15;
  const __bf16* qb = Q + (size_t)bh * Sc * HDc;
  const __bf16* kfb = Kf + (size_t)bh * 32 * 4096;
  const __bf16* vfb = Vf + (size_t)bh * 32 * 4096;
  const float* mb = mkx + (size_t)b * Sc;

  const int tid = threadIdx.x, lane = tid & 63, wid = tid >> 6;
  const int hi = lane >> 5, qr = lane & 31;

  __shared__ __attribute__((aligned(16))) __bf16 Ksm[3][4096];
  __shared__ __attribute__((aligned(16))) __bf16 Vsm[3][4096];
  __shared__ __attribute__((aligned(16))) float Msm[3][64];

  const int q0 = qt * 128 + wid * 32;

  bf16x8 qf[4];
#pragma unroll
  for (int c = 0; c < 4; ++c)
    qf[c] = *(const bf16x8*)(qb + (size_t)(q0 + qr) * HDc + c * 16 + hi * 8);

  bf16x8 onesv;
#pragma unroll
  for (int j = 0; j < 8; ++j) onesv[j] = (__bf16)1.0f;

  f32x16 oacc[2] = {};
  f32x16 lacc = {};

  // exactly 5 vmem ops per stage (uniform for vmcnt accounting)
  auto stage = [&](int buf, int t) {
    const size_t tb = (size_t)t * 4096;
    gload_lds16(kfb + tb + (size_t)tid * 8, &Ksm[buf][wid * 64 * 8]);
    gload_lds16(vfb + tb + (size_t)tid * 8, &Vsm[buf][wid * 64 * 8]);
    gload_lds16(kfb + tb + (size_t)(256 + tid) * 8, &Ksm[buf][(256 + wid * 64) * 8]);
    gload_lds16(vfb + tb + (size_t)(256 + tid) * 8, &Vsm[buf][(256 + wid * 64) * 8]);
    gload_lds4(mb + t * 64 + lane, &Msm[buf][0]);
  };

  auto body = [&](int buf) {
    const __bf16* Kb = &Ksm[buf][0] + lane * 8;
    const __bf16* Vb = &Vsm[buf][0] + lane * 8;
    const float* Mb = &Msm[buf][0];
    // C-init = mask*log2e; sacc = (QK/8 + mask)*log2e
    f32x16 sacc[2];
#pragma unroll
    for (int kb2 = 0; kb2 < 2; ++kb2) {
#pragma unroll
      for (int g = 0; g < 4; ++g) {
        const float4 m4 = *(const float4*)&Mb[kb2 * 32 + g * 8 + hi * 4];
#pragma unroll
        for (int e = 0; e < 4; ++e) sacc[kb2][g * 4 + e] = ((const float*)&m4)[e];
      }
    }
    __builtin_amdgcn_s_setprio(1);
#pragma unroll
    for (int kb2 = 0; kb2 < 2; ++kb2) {
#pragma unroll
      for (int c = 0; c < 4; ++c) {
        const bf16x8 kf = *(const bf16x8*)(Kb + (kb2 * 4 + c) * 512);
        sacc[kb2] = mfma32(kf, qf[c], sacc[kb2]);
      }
    }
    __builtin_amdgcn_s_setprio(0);

    // P = exp2(sacc); pack to bf16 A-frags via cvt_pk + permlane32_swap
    bf16x8 pa[4];
#pragma unroll
    for (int kb2 = 0; kb2 < 2; ++kb2) {
      uint32_t wv[8];
#pragma unroll
      for (int j = 0; j < 8; ++j)
        wv[j] = cvtpk_bf16(__builtin_amdgcn_exp2f(sacc[kb2][2 * j]),
                           __builtin_amdgcn_exp2f(sacc[kb2][2 * j + 1]));
#pragma unroll
      for (int cc = 0; cc < 2; ++cc) {
        i32x2_t s02 = __builtin_amdgcn_permlane32_swap(
            (int)wv[cc * 4 + 0], (int)wv[cc * 4 + 2], false, false);
        i32x2_t s13 = __builtin_amdgcn_permlane32_swap(
            (int)wv[cc * 4 + 1], (int)wv[cc * 4 + 3], false, false);
        union { uint32_t u[4]; bf16x8 v; } af;
        af.u[0] = (uint32_t)s02[0];
        af.u[1] = (uint32_t)s13[0];
        af.u[2] = (uint32_t)s02[1];
        af.u[3] = (uint32_t)s13[1];
        pa[kb2 * 2 + cc] = af.v;
      }
    }

    // PV + ones-MFMA row-sum
    __builtin_amdgcn_s_setprio(1);
#pragma unroll
    for (int kc = 0; kc < 4; ++kc) {
      lacc = mfma32(pa[kc], onesv, lacc);
#pragma unroll
      for (int nb = 0; nb < 2; ++nb) {
        const bf16x8 vf = *(const bf16x8*)(Vb + (kc * 2 + nb) * 512);
        oacc[nb] = mfma32(pa[kc], vf, oacc[nb]);
      }
    }
    __builtin_amdgcn_s_setprio(0);
  };

  stage(0, 0);
  stage(1, 1);
  int bA = 0, bB = 1, bC = 2;
  const int NT = Sc / 64;  // 32
  for (int t = 0; t < NT; ++t) {
    const int tn = (t + 2 < NT) ? (t + 2) : (NT - 1);  // dummy tail reload
    stage(bC, tn);
    __builtin_amdgcn_sched_barrier(0);
    asm volatile("s_waitcnt vmcnt(10)" ::: "memory");  // oldest 5 (cur tile) done
    __builtin_amdgcn_s_barrier();
    __builtin_amdgcn_sched_barrier(0);
    body(bA);
    __builtin_amdgcn_sched_barrier(0);
    __builtin_amdgcn_s_barrier();  // all reads of bA done before its overwrite
    const int tmp = bA; bA = bB; bB = bC; bC = tmp;
  }

  float inv[16];
#pragma unroll
  for (int r = 0; r < 16; ++r) inv[r] = __builtin_amdgcn_rcpf(lacc[r]);
#pragma unroll
  for (int nb = 0; nb < 2; ++nb) {
#pragma unroll
    for (int r = 0; r < 16; ++r) {
      const int row = (r & 3) + 8 * (r >> 2) + 4 * hi;
      const int qg = q0 + row;
      out[((size_t)b * Sc + qg) * Dc + h * HDc + nb * 32 + qr] =
          oacc[nb][r] * inv[r];
    }
  }
}

// ---------------- launch ----------------
extern "C" void kernel_launch(void* const* d_in, const int* in_sizes, int n_in,
                              void* d_out, int out_size, void* d_ws,
                              size_t ws_size, hipStream_t stream) {
  const float* hs = (const float*)d_in[0];
  const float* mask = (const float*)d_in[1];
  const float* Wq = (const float*)d_in[2];
  const float* bq = (const float*)d_in[3];
  const float* Wk = (const float*)d_in[4];
  const float* bk = (const float*)d_in[5];
  const float* Wv = (const float*)d_in[6];
  const float* bv = (const float*)d_in[7];
  float* out = (float*)d_out;

  char* ws = (char*)d_ws;
  const size_t qkv_bytes = (size_t)Bc * Hc * Sc * HDc * 2;  // 16.78 MB
  __bf16* Wt = (__bf16*)ws;                                 // 6 MB
  __bf16* Ah = (__bf16*)(ws + 6291456);
  __bf16* Q = (__bf16*)(ws + 6291456 + qkv_bytes);
  __bf16* Kf = (__bf16*)(ws + 6291456 + 2 * qkv_bytes);
  __bf16* Vf = (__bf16*)(ws + 6291456 + 3 * qkv_bytes);
  float* mkx = (float*)(ws + 6291456 + 4 * qkv_bytes);      // 32 KB

  maskscale_kernel<<<32, 256, 0, stream>>>(mask, mkx);
  hs2bf_kernel<<<4096, 256, 0, stream>>>(hs, Ah);
  wtrans_kernel<<<dim3(16, 16, 3), 256, 0, stream>>>(Wq, Wk, Wv, Wt);
  qkv_gemm_kernel<<<1536, 256, 0, stream>>>(Ah, Wt, bq, bk, bv, Q, Kf, Vf);
  attn_kernel<<<dim3(16, 64), 256, 0, stream>>>(Q, Kf, Vf, mkx, out);
}

// Round 6
// 203.263 us; speedup vs baseline: 1.0651x; 1.0388x over previous
//
#include <hip/hip_runtime.h>
#include <hip/hip_bf16.h>
#include <stdint.h>

#define Bc 4
#define Sc 2048
#define Dc 1024
#define Hc 16
#define HDc 64
#define LOG2E 1.44269504088896f

typedef __attribute__((ext_vector_type(8))) __bf16 bf16x8;
typedef __attribute__((ext_vector_type(4))) __bf16 bf16x4;
typedef __attribute__((ext_vector_type(4))) float f32x4;
typedef __attribute__((ext_vector_type(16))) float f32x16;
typedef __attribute__((ext_vector_type(2))) int i32x2_t;

__device__ __forceinline__ f32x4 mfma16(bf16x8 a, bf16x8 b, f32x4 c) {
  return __builtin_amdgcn_mfma_f32_16x16x32_bf16(a, b, c, 0, 0, 0);
}
__device__ __forceinline__ f32x16 mfma32(bf16x8 a, bf16x8 b, f32x16 c) {
  return __builtin_amdgcn_mfma_f32_32x32x16_bf16(a, b, c, 0, 0, 0);
}
__device__ __forceinline__ uint32_t cvtpk_bf16(float lo, float hi) {
  uint32_t r;
  asm("v_cvt_pk_bf16_f32 %0, %1, %2" : "=v"(r) : "v"(lo), "v"(hi));
  return r;
}
__device__ __forceinline__ void gload_lds16(const void* g, void* l) {
  __builtin_amdgcn_global_load_lds(
      (const __attribute__((address_space(1))) void*)g,
      (__attribute__((address_space(3))) void*)l, 16, 0, 0);
}
__device__ __forceinline__ void gload_lds4(const void* g, void* l) {
  __builtin_amdgcn_global_load_lds(
      (const __attribute__((address_space(1))) void*)g,
      (__attribute__((address_space(3))) void*)l, 4, 0, 0);
}

// ---------------- Kernel 0a: mask * log2e ----------------
__global__ __launch_bounds__(256) void maskscale_kernel(const float* __restrict__ m,
                                                        float* __restrict__ mkx) {
  const int i = blockIdx.x * 256 + threadIdx.x;  // 8192 total
  mkx[i] = m[i] * LOG2E;
}

// ---------------- Kernel 0b: hs (fp32) -> bf16 ----------------
__global__ __launch_bounds__(256) void hs2bf_kernel(const float* __restrict__ hs,
                                                    __bf16* __restrict__ Ah) {
  const size_t i = ((size_t)blockIdx.x * 256 + threadIdx.x) * 8;
  float4 f0 = *(const float4*)(hs + i);
  float4 f1 = *(const float4*)(hs + i + 4);
  bf16x8 o;
  o[0] = (__bf16)f0.x; o[1] = (__bf16)f0.y; o[2] = (__bf16)f0.z; o[3] = (__bf16)f0.w;
  o[4] = (__bf16)f1.x; o[5] = (__bf16)f1.y; o[6] = (__bf16)f1.z; o[7] = (__bf16)f1.w;
  *(bf16x8*)(Ah + i) = o;
}

// ---------------- Kernel 1: Wt[w][n][k] = (bf16) W[w][k][n] ----------------
__global__ __launch_bounds__(256) void wtrans_kernel(
    const float* __restrict__ Wq, const float* __restrict__ Wk,
    const float* __restrict__ Wv, __bf16* __restrict__ Wt) {
  const float* W = (blockIdx.z == 0) ? Wq : (blockIdx.z == 1 ? Wk : Wv);
  __bf16* out = Wt + (size_t)blockIdx.z * Dc * Dc;
  const int n0 = blockIdx.x * 64, k0 = blockIdx.y * 64;
  __shared__ float tile[64][65];
  const int tid = threadIdx.x;
  const int r = tid >> 2, cs = (tid & 3) * 16;
  const float* src = W + (size_t)(k0 + r) * Dc + n0 + cs;
  float4 f0 = *(const float4*)(src + 0);
  float4 f1 = *(const float4*)(src + 4);
  float4 f2 = *(const float4*)(src + 8);
  float4 f3 = *(const float4*)(src + 12);
#pragma unroll
  for (int j = 0; j < 4; ++j) {
    tile[r][cs + j] = ((const float*)&f0)[j];
    tile[r][cs + 4 + j] = ((const float*)&f1)[j];
    tile[r][cs + 8 + j] = ((const float*)&f2)[j];
    tile[r][cs + 12 + j] = ((const float*)&f3)[j];
  }
  __syncthreads();
  bf16x8 o0, o1;
#pragma unroll
  for (int j = 0; j < 8; ++j) {
    o0[j] = (__bf16)tile[cs + j][r];
    o1[j] = (__bf16)tile[cs + 8 + j][r];
  }
  __bf16* dst = out + (size_t)(n0 + r) * Dc + k0 + cs;
  *(bf16x8*)(dst) = o0;
  *(bf16x8*)(dst + 8) = o1;
}

// ---------------- Kernel 2: fused QKV GEMM ----------------
// Q: [B,H,S,HD] pre-scaled by log2e/8.
// K: fragment-order Kf[bh][t][slot]*8+j8, slot=(kt>>5)*256+c*64+shi*32+(kt&31),
//    element j8 holds K[key=t*64+kb2*32+sqr][hd=c*16+shi*8+j8].
// V: fragment-order Vf[bh][t][slot]*8+j,  slot=kc*128+nb*64+shi*32+sqr,
//    element j holds V[key=t*64+kc*16+shi*8+j][hd=nb*32+sqr].
__global__ __launch_bounds__(256) void qkv_gemm_kernel(
    const __bf16* __restrict__ A, const __bf16* __restrict__ Wt,
    const float* __restrict__ bq, const float* __restrict__ bk,
    const float* __restrict__ bv,
    __bf16* __restrict__ Qo, __bf16* __restrict__ Kf, __bf16* __restrict__ Vf) {
  const int orig = blockIdx.x;
  const int nt = orig & 7;
  const int rest = orig >> 3;        // 0..191
  const int w = rest >> 6;           // 0..2
  const int mt = rest & 63;          // 0..63
  const int m0 = mt * 128, n0 = nt * 128;

  const __bf16* Bp = Wt + (size_t)w * Dc * Dc;
  const float* bias = (w == 0) ? bq : (w == 1 ? bk : bv);

  __shared__ __attribute__((aligned(16))) __bf16 Asm[2][128 * 32];
  __shared__ __attribute__((aligned(16))) __bf16 Bsm[2][128 * 32];

  const int tid = threadIdx.x, lane = tid & 63, wid = tid >> 6;
  const int wm = wid >> 1, wn = wid & 1;
  const int lg = lane >> 4, li = lane & 15;

  f32x4 acc[4][4] = {};

  auto stage = [&](int buf, int k0) {
#pragma unroll
    for (int i = 0; i < 2; ++i) {
      const int u = i * 256 + tid;
      const int row = u >> 2, c = u & 3;
      const int gc = c ^ (row & 3);
      gload_lds16(A + (size_t)(m0 + row) * Dc + k0 + gc * 8,
                  &Asm[buf][i * 2048 + wid * 512]);
      gload_lds16(Bp + (size_t)(n0 + row) * Dc + k0 + gc * 8,
                  &Bsm[buf][i * 2048 + wid * 512]);
    }
  };

  int cur = 0;
  stage(0, 0);
  __syncthreads();

  for (int k0 = 0; k0 < Dc; k0 += 32) {
    if (k0 + 32 < Dc) stage(cur ^ 1, k0 + 32);
    bf16x8 af[4], bfr[4];
#pragma unroll
    for (int i = 0; i < 4; ++i) {
      const int rowa = wm * 64 + i * 16 + li;
      af[i] = *(const bf16x8*)&Asm[cur][rowa * 32 + (lg ^ (rowa & 3)) * 8];
      const int rowb = wn * 64 + i * 16 + li;
      bfr[i] = *(const bf16x8*)&Bsm[cur][rowb * 32 + (lg ^ (rowb & 3)) * 8];
    }
#pragma unroll
    for (int i = 0; i < 4; ++i)
#pragma unroll
      for (int j = 0; j < 4; ++j)
        acc[i][j] = mfma16(af[i], bfr[j], acc[i][j]);
    __syncthreads();
    cur ^= 1;
  }

  if (w == 0) {
    const float scl = 0.125f * LOG2E;
#pragma unroll
    for (int i = 0; i < 4; ++i) {
#pragma unroll
      for (int j = 0; j < 4; ++j) {
        const int n = n0 + wn * 64 + j * 16 + li;
        const float bb = bias[n];
        const int h = n >> 6, hd = n & 63;
#pragma unroll
        for (int r = 0; r < 4; ++r) {
          const int m = m0 + wm * 64 + i * 16 + lg * 4 + r;
          const int b = m >> 11, s = m & 2047;
          Qo[(((size_t)b * Hc + h) * Sc + s) * HDc + hd] =
              (__bf16)((acc[i][j][r] + bb) * scl);
        }
      }
    }
  } else if (w == 1) {
    // K fragment-order scatter (2B stores, same count as plain layout)
#pragma unroll
    for (int j = 0; j < 4; ++j) {
      const int n = n0 + wn * 64 + j * 16 + li;
      const float bb = bias[n];
      const int h = n >> 6, hd = n & 63;
      const int c = hd >> 4, shi = (hd >> 3) & 1, j8 = hd & 7;
#pragma unroll
      for (int i = 0; i < 4; ++i) {
#pragma unroll
        for (int r = 0; r < 4; ++r) {
          const int m = m0 + wm * 64 + i * 16 + lg * 4 + r;
          const int b = m >> 11, s = m & 2047;
          const int bh = b * Hc + h;
          const int t = s >> 6, kt = s & 63;
          const int slot = (kt >> 5) * 256 + c * 64 + shi * 32 + (kt & 31);
          Kf[((size_t)(bh * 32 + t)) * 4096 + slot * 8 + j8] =
              (__bf16)(acc[i][j][r] + bb);
        }
      }
    }
  } else {
    // V fragment-order: 4 consecutive keys per lane -> 8B store
#pragma unroll
    for (int i = 0; i < 4; ++i) {
      const int mbase = m0 + wm * 64 + i * 16 + lg * 4;
      const int b = mbase >> 11, sk = mbase & 2047;
      const int t = sk >> 6, kt = sk & 63;
      const int kc = kt >> 4, shi = (kt >> 3) & 1, j0 = kt & 7;  // j0 in {0,4}
#pragma unroll
      for (int j = 0; j < 4; ++j) {
        const int n = n0 + wn * 64 + j * 16 + li;
        const float bb = bias[n];
        const int h = n >> 6, hd = n & 63;
        const int nb = hd >> 5, sqr = hd & 31;
        const int bh = b * Hc + h;
        const int slot = kc * 128 + nb * 64 + shi * 32 + sqr;
        bf16x4 o;
#pragma unroll
        for (int r = 0; r < 4; ++r) o[r] = (__bf16)(acc[i][j][r] + bb);
        *(bf16x4*)&Vf[((size_t)(bh * 32 + t)) * 4096 + slot * 8 + j0] = o;
      }
    }
  }
}

// ---------------- Kernel 3: attention (T15 pipelined) ----------------
// Swapped-QK in-register softmax; K/V in fragment order in global (linear
// coalesced gload_lds, zero LDS conflicts). 4 LDS buffers, 3-tile-ahead
// prefetch, counted vmcnt. Pipeline: QK(t+1) [MFMA] issues BEFORE
// exp/pack(t) [VALU] so the two pipes overlap within each wave.
__global__ __launch_bounds__(256) void attn_kernel(
    const __bf16* __restrict__ Q, const __bf16* __restrict__ Kf,
    const __bf16* __restrict__ Vf, const float* __restrict__ mkx,
    float* __restrict__ out) {
  const int qt = blockIdx.x;   // 0..15
  const int bh = blockIdx.y;   // 0..63
  const int b = bh >> 4, h = bh & 15;
  const __bf16* qb = Q + (size_t)bh * Sc * HDc;
  const __bf16* kfb = Kf + (size_t)bh * 32 * 4096;
  const __bf16* vfb = Vf + (size_t)bh * 32 * 4096;
  const float* mb = mkx + (size_t)b * Sc;

  const int tid = threadIdx.x, lane = tid & 63, wid = tid >> 6;
  const int hi = lane >> 5, qr = lane & 31;

  __shared__ __attribute__((aligned(16))) __bf16 Ksm[4][4096];
  __shared__ __attribute__((aligned(16))) __bf16 Vsm[4][4096];
  __shared__ __attribute__((aligned(16))) float Msm[4][64];

  const int q0 = qt * 128 + wid * 32;

  bf16x8 qf[4];
#pragma unroll
  for (int c = 0; c < 4; ++c)
    qf[c] = *(const bf16x8*)(qb + (size_t)(q0 + qr) * HDc + c * 16 + hi * 8);

  bf16x8 onesv;
#pragma unroll
  for (int j = 0; j < 8; ++j) onesv[j] = (__bf16)1.0f;

  f32x16 oacc[2] = {};
  f32x16 lacc = {};
  f32x16 sA[2], sB[2];

  // exactly 5 vmem ops per stage (uniform for vmcnt accounting)
  auto stage = [&](int buf, int t) {
    const size_t tb = (size_t)t * 4096;
    gload_lds16(kfb + tb + (size_t)tid * 8, &Ksm[buf][wid * 64 * 8]);
    gload_lds16(vfb + tb + (size_t)tid * 8, &Vsm[buf][wid * 64 * 8]);
    gload_lds16(kfb + tb + (size_t)(256 + tid) * 8, &Ksm[buf][(256 + wid * 64) * 8]);
    gload_lds16(vfb + tb + (size_t)(256 + tid) * 8, &Vsm[buf][(256 + wid * 64) * 8]);
    gload_lds4(mb + t * 64 + lane, &Msm[buf][0]);
  };

  // QK^T of one tile into s[2] (C-init = mask*log2e)
  auto qk = [&](int buf, f32x16 (&s)[2]) {
    const __bf16* Kb = &Ksm[buf][0] + lane * 8;
    const float* Mb = &Msm[buf][0];
#pragma unroll
    for (int kb2 = 0; kb2 < 2; ++kb2) {
#pragma unroll
      for (int g = 0; g < 4; ++g) {
        const float4 m4 = *(const float4*)&Mb[kb2 * 32 + g * 8 + hi * 4];
#pragma unroll
        for (int e = 0; e < 4; ++e) s[kb2][g * 4 + e] = ((const float*)&m4)[e];
      }
    }
    __builtin_amdgcn_s_setprio(1);
#pragma unroll
    for (int kb2 = 0; kb2 < 2; ++kb2) {
#pragma unroll
      for (int c = 0; c < 4; ++c) {
        const bf16x8 kf = *(const bf16x8*)(Kb + (kb2 * 4 + c) * 512);
        s[kb2] = mfma32(kf, qf[c], s[kb2]);
      }
    }
    __builtin_amdgcn_s_setprio(0);
  };

  // exp2 + pack + PV of one tile from s[2]
  auto softpv = [&](int buf, f32x16 (&s)[2]) {
    const __bf16* Vb = &Vsm[buf][0] + lane * 8;
    bf16x8 pa[4];
#pragma unroll
    for (int kb2 = 0; kb2 < 2; ++kb2) {
      uint32_t wv[8];
#pragma unroll
      for (int j = 0; j < 8; ++j)
        wv[j] = cvtpk_bf16(__builtin_amdgcn_exp2f(s[kb2][2 * j]),
                           __builtin_amdgcn_exp2f(s[kb2][2 * j + 1]));
#pragma unroll
      for (int cc = 0; cc < 2; ++cc) {
        i32x2_t s02 = __builtin_amdgcn_permlane32_swap(
            (int)wv[cc * 4 + 0], (int)wv[cc * 4 + 2], false, false);
        i32x2_t s13 = __builtin_amdgcn_permlane32_swap(
            (int)wv[cc * 4 + 1], (int)wv[cc * 4 + 3], false, false);
        union { uint32_t u[4]; bf16x8 v; } af;
        af.u[0] = (uint32_t)s02[0];
        af.u[1] = (uint32_t)s13[0];
        af.u[2] = (uint32_t)s02[1];
        af.u[3] = (uint32_t)s13[1];
        pa[kb2 * 2 + cc] = af.v;
      }
    }
    __builtin_amdgcn_s_setprio(1);
#pragma unroll
    for (int kc = 0; kc < 4; ++kc) {
      lacc = mfma32(pa[kc], onesv, lacc);
#pragma unroll
      for (int nb = 0; nb < 2; ++nb) {
        const bf16x8 vf = *(const bf16x8*)(Vb + (kc * 2 + nb) * 512);
        oacc[nb] = mfma32(pa[kc], vf, oacc[nb]);
      }
    }
    __builtin_amdgcn_s_setprio(0);
  };

  const int NT = Sc / 64;  // 32, divisible by 4

  stage(0, 0);
  stage(1, 1);
  stage(2, 2);
  __builtin_amdgcn_sched_barrier(0);
  asm volatile("s_waitcnt vmcnt(10)" ::: "memory");  // tile 0 landed
  __builtin_amdgcn_s_barrier();
  __builtin_amdgcn_sched_barrier(0);
  qk(0, sA);

#define ITER(T, SB, QB, PB, CUR, NXT)                                   \
  {                                                                     \
    const int t_ = (T);                                                 \
    const int tn_ = (t_ + 3 < NT) ? t_ + 3 : NT - 1;                    \
    stage(SB, tn_);                                                     \
    __builtin_amdgcn_sched_barrier(0);                                  \
    asm volatile("s_waitcnt vmcnt(10)" ::: "memory"); /* t+1 landed */  \
    __builtin_amdgcn_s_barrier();                                       \
    __builtin_amdgcn_sched_barrier(0);                                  \
    qk(QB, NXT);   /* MFMA: scores of tile t+1 (dummy at t=NT-1) */     \
    softpv(PB, CUR); /* VALU exp(t) overlaps qk's MFMAs, then PV(t) */  \
    __builtin_amdgcn_sched_barrier(0);                                  \
    __builtin_amdgcn_s_barrier(); /* buf PB reads done before reuse */  \
  }

  for (int t4 = 0; t4 < NT; t4 += 4) {
    ITER(t4 + 0, 3, 1, 0, sA, sB);
    ITER(t4 + 1, 0, 2, 1, sB, sA);
    ITER(t4 + 2, 1, 3, 2, sA, sB);
    ITER(t4 + 3, 2, 0, 3, sB, sA);
  }
#undef ITER

  float inv[16];
#pragma unroll
  for (int r = 0; r < 16; ++r) inv[r] = __builtin_amdgcn_rcpf(lacc[r]);
#pragma unroll
  for (int nb = 0; nb < 2; ++nb) {
#pragma unroll
    for (int r = 0; r < 16; ++r) {
      const int row = (r & 3) + 8 * (r >> 2) + 4 * hi;
      const int qg = q0 + row;
      out[((size_t)b * Sc + qg) * Dc + h * HDc + nb * 32 + qr] =
          oacc[nb][r] * inv[r];
    }
  }
}

// ---------------- launch ----------------
extern "C" void kernel_launch(void* const* d_in, const int* in_sizes, int n_in,
                              void* d_out, int out_size, void* d_ws,
                              size_t ws_size, hipStream_t stream) {
  const float* hs = (const float*)d_in[0];
  const float* mask = (const float*)d_in[1];
  const float* Wq = (const float*)d_in[2];
  const float* bq = (const float*)d_in[3];
  const float* Wk = (const float*)d_in[4];
  const float* bk = (const float*)d_in[5];
  const float* Wv = (const float*)d_in[6];
  const float* bv = (const float*)d_in[7];
  float* out = (float*)d_out;

  char* ws = (char*)d_ws;
  const size_t qkv_bytes = (size_t)Bc * Hc * Sc * HDc * 2;  // 16.78 MB
  __bf16* Wt = (__bf16*)ws;                                 // 6 MB
  __bf16* Ah = (__bf16*)(ws + 6291456);
  __bf16* Q = (__bf16*)(ws + 6291456 + qkv_bytes);
  __bf16* Kf = (__bf16*)(ws + 6291456 + 2 * qkv_bytes);
  __bf16* Vf = (__bf16*)(ws + 6291456 + 3 * qkv_bytes);
  float* mkx = (float*)(ws + 6291456 + 4 * qkv_bytes);      // 32 KB

  maskscale_kernel<<<32, 256, 0, stream>>>(mask, mkx);
  hs2bf_kernel<<<4096, 256, 0, stream>>>(hs, Ah);
  wtrans_kernel<<<dim3(16, 16, 3), 256, 0, stream>>>(Wq, Wk, Wv, Wt);
  qkv_gemm_kernel<<<1536, 256, 0, stream>>>(Ah, Wt, bq, bk, bv, Q, Kf, Vf);
  attn_kernel<<<dim3(16, 64), 256, 0, stream>>>(Q, Kf, Vf, mkx, out);
}